// Round 3
// baseline (126.887 us; speedup 1.0000x reference)
//
#include <hip/hip_runtime.h>

#define NSUB   10000
#define NCLS   17
#define NG     500
#define NE     80000
#define HIDN   8
#define CWLD   52          // 0..16 = 1/Var, 17..33 = Mu/Var, 34..41 = W_l, 42..49 = W_r, 50/51 pad
#define NEG_SLOPE 0.2f

// ws layout (in floats)
#define OFF_CW   0                      // NG*CWLD = 26000
#define OFF_D    (OFF_CW + NG*CWLD)     // 32
#define OFF_XL   (OFF_D + 32)           // NSUB*8
#define OFF_XR   (OFF_XL + NSUB*HIDN)   // NSUB*8
#define OFF_LP   (OFF_XR + NSUB*HIDN)   // NSUB*17
#define OFF_E    (OFF_LP + NSUB*NCLS)   // NE
#define OFF_MORD (OFF_E + NE)           // NSUB (uint)
#define OFF_NUM  (OFF_MORD + NSUB)      // NSUB
#define OFF_DEN  (OFF_NUM + NSUB)       // NSUB

// ---------------- prep: build CW[g][52], D[c], and zero all accumulators ----------------
__global__ void k_prep(const float* __restrict__ Mu, const float* __restrict__ Var,
                       const float* __restrict__ Wl, const float* __restrict__ Wr,
                       float* __restrict__ CW, float* __restrict__ D,
                       float* __restrict__ zeroBase, float* __restrict__ out) {
    const int b = blockIdx.x;
    if (b < 2) {
        const int g = b * 256 + threadIdx.x;
        if (g < NG) {
            float* row = CW + g * CWLD;
            #pragma unroll
            for (int c = 0; c < NCLS; c++) {
                const float iv = 1.0f / Var[c * NG + g];
                row[c]        = iv;
                row[NCLS + c] = Mu[c * NG + g] * iv;
            }
            #pragma unroll
            for (int h = 0; h < HIDN; h++) {
                row[34 + h] = Wl[g * HIDN + h];
                row[42 + h] = Wr[g * HIDN + h];
            }
            row[50] = 0.f; row[51] = 0.f;
        }
    } else if (b < 19) {
        const int c = b - 2;           // 17 classes
        float s = 0.f;
        for (int g = threadIdx.x; g < NG; g += 256) {
            const float m = Mu[c * NG + g];
            s += m * m / Var[c * NG + g];
        }
        __shared__ float red[4];
        #pragma unroll
        for (int o = 32; o; o >>= 1) s += __shfl_xor(s, o);
        const int w = threadIdx.x >> 6, l = threadIdx.x & 63;
        if (l == 0) red[w] = s;
        __syncthreads();
        if (threadIdx.x == 0) D[c] = red[0] + red[1] + red[2] + red[3];
    } else {
        // zero MORD/NUM/DEN (3*NSUB contiguous floats) + out[0], out[1]
        const int i = (b - 19) * 256 + threadIdx.x;
        if (i < 3 * NSUB) zeroBase[i] = 0.f;
        if (b == 19 && threadIdx.x < 2) out[threadIdx.x] = 0.f;
    }
}

// ---- per-cell: scalar-pipe B-operand GEMM + softmax + ll_prot + xl/xr + logP ----
// block = 256 threads = 4 waves over the SAME 64 cells (lane = cell).
// Gene split across waves: 124/124/124/128 (starts 16B-aligned).
// B (CW) addresses are wave-uniform -> compiler promotes to s_load (scalar pipe),
// FMAs read SGPR operands directly; VALU becomes the critical path.
__launch_bounds__(256)
__global__ void k_cell(const float* __restrict__ x, const int* __restrict__ sidx,
                       const float* __restrict__ Wp, const float* __restrict__ Sp,
                       const float* __restrict__ bl, const float* __restrict__ br,
                       const float* __restrict__ CW, const float* __restrict__ D,
                       float* __restrict__ out, float* __restrict__ XL,
                       float* __restrict__ XR, float* __restrict__ LP) {
    const int w = threadIdx.x >> 6, l = threadIdx.x & 63;
    const int cell = blockIdx.x * 64 + l;
    const bool live = (cell < NSUB);

    float acc[50];
    #pragma unroll
    for (int i = 0; i < 50; i++) acc[i] = 0.f;

    // wave-uniform gene range (readfirstlane makes it provably uniform)
    const int w_u  = __builtin_amdgcn_readfirstlane(w);
    const int g0   = w_u * 124;
    const int gcnt = (w_u == 3) ? 128 : 124;

    const int crow = live ? cell : (NSUB - 1);     // clamp (dead lanes discarded later)
    const float* xrow = x + (size_t)crow * NG + g0;
    const float* cw0  = CW + (size_t)g0 * CWLD;

    for (int i = 0; i < gcnt; i += 4) {
        const float4 xv = *reinterpret_cast<const float4*>(xrow + i);
        #pragma unroll
        for (int j = 0; j < 4; j++) {
            const float xs = (&xv.x)[j];
            const float x2 = xs * xs;
            const float* c2 = cw0 + (size_t)(i + j) * CWLD;   // wave-uniform address
            #pragma unroll
            for (int q = 0; q < 13; q++) {
                const float4 v = *reinterpret_cast<const float4*>(c2 + 4 * q);
                #pragma unroll
                for (int k = 0; k < 4; k++) {
                    const int idx = 4 * q + k;
                    if (idx < 50)
                        acc[idx] += ((idx < NCLS) ? x2 : xs) * (&v.x)[k];
                }
            }
        }
    }

    // 2-step cross-wave reduce (lane = cell), stride 51 (odd) -> conflict-free
    __shared__ float lds[2 * 64 * 51];
    if (w >= 2) { float* p = lds + (size_t)((w - 2) * 64 + l) * 51;
        #pragma unroll
        for (int i = 0; i < 50; i++) p[i] = acc[i]; }
    __syncthreads();
    if (w < 2)  { const float* p = lds + (size_t)(w * 64 + l) * 51;
        #pragma unroll
        for (int i = 0; i < 50; i++) acc[i] += p[i]; }
    __syncthreads();
    if (w == 1) { float* p = lds + (size_t)l * 51;
        #pragma unroll
        for (int i = 0; i < 50; i++) p[i] = acc[i]; }
    __syncthreads();

    if (w == 0) {
        float ll = 0.f;
        if (live) {
            const float* p2 = lds + (size_t)l * 51;
            #pragma unroll
            for (int i = 0; i < 50; i++) acc[i] += p2[i];

            const int idx = sidx[cell];
            const float* wrow = Wp + (size_t)idx * NCLS;
            float p[NCLS];
            float mx = -1e30f;
            #pragma unroll
            for (int c = 0; c < NCLS; c++) { p[c] = wrow[c]; mx = fmaxf(mx, p[c]); }
            float sum = 0.f;
            #pragma unroll
            for (int c = 0; c < NCLS; c++) { p[c] = __expf(p[c] - mx); sum += p[c]; }
            const float inv = 1.0f / sum;
            const float s = Sp[idx];
            float* orow = out + 2 + (size_t)cell * NCLS;
            float* lrow = LP + (size_t)cell * NCLS;
            #pragma unroll
            for (int c = 0; c < NCLS; c++) {
                p[c] *= inv;
                orow[c] = p[c];
                lrow[c] = __logf(p[c] + 1e-8f);
                const float F = -0.5f * acc[c] + s * acc[NCLS + c] - 0.5f * s * s * D[c];
                ll += p[c] * F;
            }
            #pragma unroll
            for (int h = 0; h < HIDN; h++) {
                XL[cell * HIDN + h] = acc[34 + h] + bl[h];
                XR[cell * HIDN + h] = acc[42 + h] + br[h];
            }
        }
        #pragma unroll
        for (int o = 32; o; o >>= 1) ll += __shfl_xor(ll, o);
        if (l == 0) atomicAdd(out, ll * (1.0f / NSUB));
    }
}

// ---------------- edge pass 1: e_k and segment max over dst ----------------
__device__ __forceinline__ unsigned f2ord(float f) {
    unsigned u = __float_as_uint(f);
    return (u & 0x80000000u) ? ~u : (u | 0x80000000u);
}
__device__ __forceinline__ float ord2f(unsigned o) {
    unsigned u = (o & 0x80000000u) ? (o ^ 0x80000000u) : ~o;
    return __uint_as_float(u);
}

__global__ void k_edge1(const int* __restrict__ ei, const float* __restrict__ XL,
                        const float* __restrict__ XR, const float* __restrict__ att,
                        float* __restrict__ E, unsigned* __restrict__ MORD) {
    const int k = blockIdx.x * 256 + threadIdx.x;
    if (k >= NE) return;
    const int s = ei[k], d = ei[NE + k];
    const float4 a0 = *reinterpret_cast<const float4*>(XL + s * HIDN);
    const float4 a1 = *reinterpret_cast<const float4*>(XL + s * HIDN + 4);
    const float4 b0 = *reinterpret_cast<const float4*>(XR + d * HIDN);
    const float4 b1 = *reinterpret_cast<const float4*>(XR + d * HIDN + 4);
    float hv[8] = { a0.x + b0.x, a0.y + b0.y, a0.z + b0.z, a0.w + b0.w,
                    a1.x + b1.x, a1.y + b1.y, a1.z + b1.z, a1.w + b1.w };
    float e = 0.f;
    #pragma unroll
    for (int h = 0; h < HIDN; h++) {
        float v = hv[h];
        v = (v > 0.f) ? v : NEG_SLOPE * v;
        e += v * att[h];
    }
    E[k] = e;
    atomicMax(MORD + d, f2ord(e));
}

// ---------------- edge pass 2: exp + weighted accumulation ----------------
__global__ void k_edge2(const int* __restrict__ ei, const float* __restrict__ out,
                        const float* __restrict__ LP, const float* __restrict__ E,
                        const unsigned* __restrict__ MORD,
                        float* __restrict__ NUM, float* __restrict__ DEN) {
    const int k = blockIdx.x * 256 + threadIdx.x;
    if (k >= NE) return;
    const int s = ei[k], d = ei[NE + k];
    const float m = ord2f(MORD[d]);
    const float ex = __expf(E[k] - m);
    const float* Ps = out + 2 + (size_t)s * NCLS;
    const float* Ld = LP + (size_t)d * NCLS;
    float wgt = 0.f;
    #pragma unroll
    for (int c = 0; c < NCLS; c++) wgt += Ps[c] * Ld[c];
    atomicAdd(NUM + d, ex * wgt);
    atomicAdd(DEN + d, ex);
}

// ---------------- node pass: ce_space = -sum(num/den)/n ----------------
__global__ void k_node(const float* __restrict__ NUM, const float* __restrict__ DEN,
                       float* __restrict__ out) {
    const int n = blockIdx.x * 256 + threadIdx.x;
    float v = 0.f;
    if (n < NSUB) {
        const float dd = DEN[n];
        if (dd > 0.f) v = NUM[n] / dd;
    }
    #pragma unroll
    for (int o = 32; o; o >>= 1) v += __shfl_xor(v, o);
    if ((threadIdx.x & 63) == 0) atomicAdd(out + 1, -v * (1.0f / NSUB));
}

extern "C" void kernel_launch(void* const* d_in, const int* in_sizes, int n_in,
                              void* d_out, int out_size, void* d_ws, size_t ws_size,
                              hipStream_t stream) {
    const float* x    = (const float*)d_in[0];
    const float* Mu   = (const float*)d_in[1];
    const float* Var  = (const float*)d_in[2];
    const int*   ei   = (const int*)d_in[3];
    const int*   sidx = (const int*)d_in[4];
    const float* Wp   = (const float*)d_in[5];
    const float* Sp   = (const float*)d_in[6];
    const float* Wl   = (const float*)d_in[7];
    const float* bl   = (const float*)d_in[8];
    const float* Wr   = (const float*)d_in[9];
    const float* br   = (const float*)d_in[10];
    const float* att  = (const float*)d_in[11];
    float* out = (float*)d_out;
    float* ws  = (float*)d_ws;

    float*    CW   = ws + OFF_CW;
    float*    D    = ws + OFF_D;
    float*    XL   = ws + OFF_XL;
    float*    XR   = ws + OFF_XR;
    float*    LP   = ws + OFF_LP;
    float*    E    = ws + OFF_E;
    unsigned* MORD = (unsigned*)(ws + OFF_MORD);
    float*    NUM  = ws + OFF_NUM;
    float*    DEN  = ws + OFF_DEN;

    (void)in_sizes; (void)n_in; (void)out_size; (void)ws_size;

    // k_prep blocks: 2 (CW) + 17 (D) + ceil(3*NSUB/256)=118 (zeroing)
    k_prep<<<19 + (3 * NSUB + 255) / 256, 256, 0, stream>>>(Mu, Var, Wl, Wr, CW, D,
                                                            ws + OFF_MORD, out);
    k_cell<<<(NSUB + 63) / 64, 256, 0, stream>>>(x, sidx, Wp, Sp, bl, br, CW, D,
                                                 out, XL, XR, LP);
    k_edge1<<<(NE + 255) / 256, 256, 0, stream>>>(ei, XL, XR, att, E, MORD);
    k_edge2<<<(NE + 255) / 256, 256, 0, stream>>>(ei, out, LP, E, MORD, NUM, DEN);
    k_node<<<(NSUB + 255) / 256, 256, 0, stream>>>(NUM, DEN, out);
}

// Round 4
// 55.760 us; speedup vs baseline: 2.2756x; 2.2756x over previous
//
#include <hip/hip_runtime.h>

#define NSUB   10000
#define NCLS   17
#define NG     500
#define NE     80000
#define HIDN   8
#define NEG_SLOPE 0.2f

typedef __attribute__((ext_vector_type(8))) short short8;
typedef __attribute__((ext_vector_type(4))) float f32x4;

// ws layout (in floats)
#define OFF_B1   0                        // 32768 ushort = 16384 float slots
#define OFF_B2   16384                    // 16384 ushort = 8192 float slots
#define OFF_D    (OFF_B2 + 8192)          // 32
#define OFF_XL   (OFF_D + 32)             // NSUB*8
#define OFF_XR   (OFF_XL + NSUB*HIDN)     // NSUB*8
#define OFF_LP   (OFF_XR + NSUB*HIDN)     // NSUB*17
#define OFF_E    (OFF_LP + NSUB*NCLS)     // NE
#define OFF_MORD (OFF_E + NE)             // NSUB (uint)
#define OFF_NUM  (OFF_MORD + NSUB)        // NSUB
#define OFF_DEN  (OFF_NUM + NSUB)         // NSUB

__device__ __forceinline__ unsigned short f2bf(float f) {
    unsigned u = __float_as_uint(f);
    u += 0x7FFFu + ((u >> 16) & 1u);      // round-to-nearest-even
    return (unsigned short)(u >> 16);
}

// ---- prep: build B1/B2 in MFMA fragment layout (bf16), D[c], zero accumulators ----
// B1[k][n] (k=0..511 pad, n=0..63): n in 17..33 -> Mu/Var[n-17][k]; 34..41 -> Wl[k][n-34];
//                                   42..49 -> Wr[k][n-42]; else 0.
// B2[k][n] (n=0..31): n<17 -> 1/Var[n][k]; else 0.
// Fragment: lane holds col=(lane&15)+nt*16, k = ks*32 + (lane>>4)*8 + e (e=0..7 packed 16B).
__global__ void k_prep(const float* __restrict__ Mu, const float* __restrict__ Var,
                       const float* __restrict__ Wl, const float* __restrict__ Wr,
                       unsigned short* __restrict__ B1, unsigned short* __restrict__ B2,
                       float* __restrict__ D, float* __restrict__ zeroBase,
                       float* __restrict__ out) {
    const int b = blockIdx.x;
    if (b < 4) {
        const int t = b * 256 + threadIdx.x;        // 1024 threads = 16 ksteps * 64 lanes
        const int ks = t >> 6, lane = t & 63;
        const int grp = lane >> 4, j = lane & 15;
        unsigned short v1[4][8], v2[2][8];
        #pragma unroll
        for (int e = 0; e < 8; e++) {
            const int g = ks * 32 + grp * 8 + e;
            const bool gv = (g < NG);
            #pragma unroll
            for (int nt = 0; nt < 4; nt++) {
                const int col = nt * 16 + j;
                float v = 0.f;
                if (gv) {
                    if (col >= 17 && col < 34)      v = Mu[(col - 17) * NG + g] / Var[(col - 17) * NG + g];
                    else if (col >= 34 && col < 42) v = Wl[g * HIDN + (col - 34)];
                    else if (col >= 42 && col < 50) v = Wr[g * HIDN + (col - 42)];
                }
                v1[nt][e] = f2bf(v);
            }
            #pragma unroll
            for (int nt = 0; nt < 2; nt++) {
                const int col = nt * 16 + j;
                float v = 0.f;
                if (gv && col < NCLS) v = 1.0f / Var[col * NG + g];
                v2[nt][e] = f2bf(v);
            }
        }
        #pragma unroll
        for (int nt = 0; nt < 4; nt++)
            *reinterpret_cast<short8*>(B1 + (size_t)(((ks * 4 + nt) * 64 + lane)) * 8) =
                *reinterpret_cast<short8*>(v1[nt]);
        #pragma unroll
        for (int nt = 0; nt < 2; nt++)
            *reinterpret_cast<short8*>(B2 + (size_t)(((ks * 2 + nt) * 64 + lane)) * 8) =
                *reinterpret_cast<short8*>(v2[nt]);
    } else if (b < 21) {
        const int c = b - 4;           // 17 classes
        float s = 0.f;
        for (int g = threadIdx.x; g < NG; g += 256) {
            const float m = Mu[c * NG + g];
            s += m * m / Var[c * NG + g];
        }
        __shared__ float red[4];
        #pragma unroll
        for (int o = 32; o; o >>= 1) s += __shfl_xor(s, o);
        const int w = threadIdx.x >> 6, l = threadIdx.x & 63;
        if (l == 0) red[w] = s;
        __syncthreads();
        if (threadIdx.x == 0) D[c] = red[0] + red[1] + red[2] + red[3];
    } else {
        const int i = (b - 21) * 256 + threadIdx.x;
        if (i < 3 * NSUB) zeroBase[i] = 0.f;
        if (b == 21 && threadIdx.x < 2) out[threadIdx.x] = 0.f;
    }
}

// ---- per-cell: MFMA GEMM (16 rows x 64 cols per wave) + epilogue ----
__launch_bounds__(256)
__global__ void k_cell(const float* __restrict__ x, const int* __restrict__ sidx,
                       const float* __restrict__ Wp, const float* __restrict__ Sp,
                       const float* __restrict__ bl, const float* __restrict__ br,
                       const unsigned short* __restrict__ B1,
                       const unsigned short* __restrict__ B2,
                       const float* __restrict__ D,
                       float* __restrict__ out, float* __restrict__ XL,
                       float* __restrict__ XR, float* __restrict__ LP) {
    const int w = threadIdx.x >> 6, l = threadIdx.x & 63;
    const int grp = l >> 4, j = l & 15;
    const int rowbase = blockIdx.x * 64 + w * 16;
    const int acell = rowbase + j;                       // row this lane loads for A
    const int crow  = (acell < NSUB) ? acell : (NSUB - 1);

    f32x4 acc0 = {0,0,0,0}, acc1 = {0,0,0,0}, acc2 = {0,0,0,0}, acc3 = {0,0,0,0};

    const float* xr = x + (size_t)crow * NG;
    const short8* b1 = reinterpret_cast<const short8*>(B1);
    const short8* b2 = reinterpret_cast<const short8*>(B2);

    #pragma unroll 3
    for (int ks = 0; ks < 15; ks++) {
        const int g0 = ks * 32 + grp * 8;
        const float4 v0 = *reinterpret_cast<const float4*>(xr + g0);
        const float4 v1 = *reinterpret_cast<const float4*>(xr + g0 + 4);
        const float xv[8] = { v0.x, v0.y, v0.z, v0.w, v1.x, v1.y, v1.z, v1.w };
        short8 a, a2;
        #pragma unroll
        for (int e = 0; e < 8; e++) {
            a[e]  = (short)f2bf(xv[e]);
            a2[e] = (short)f2bf(xv[e] * xv[e]);
        }
        const short8* p1 = b1 + (size_t)(ks * 4) * 64 + l;
        const short8* p2 = b2 + (size_t)(ks * 2) * 64 + l;
        acc0 = __builtin_amdgcn_mfma_f32_16x16x32_bf16(a,  p1[0],   acc0, 0, 0, 0);
        acc1 = __builtin_amdgcn_mfma_f32_16x16x32_bf16(a,  p1[64],  acc1, 0, 0, 0);
        acc2 = __builtin_amdgcn_mfma_f32_16x16x32_bf16(a,  p1[128], acc2, 0, 0, 0);
        acc3 = __builtin_amdgcn_mfma_f32_16x16x32_bf16(a,  p1[192], acc3, 0, 0, 0);
        acc0 = __builtin_amdgcn_mfma_f32_16x16x32_bf16(a2, p2[0],   acc0, 0, 0, 0);
        acc1 = __builtin_amdgcn_mfma_f32_16x16x32_bf16(a2, p2[64],  acc1, 0, 0, 0);
    }
    {   // ks = 15: genes 480..511, valid < 500. g0 in {480,488,496,504}
        const int g0 = 480 + grp * 8;
        float xv[8];
        if (g0 <= 496) {
            const float4 v0 = *reinterpret_cast<const float4*>(xr + g0);
            xv[0] = v0.x; xv[1] = v0.y; xv[2] = v0.z; xv[3] = v0.w;
        } else { xv[0] = xv[1] = xv[2] = xv[3] = 0.f; }
        if (g0 <= 488) {
            const float4 v1 = *reinterpret_cast<const float4*>(xr + g0 + 4);
            xv[4] = v1.x; xv[5] = v1.y; xv[6] = v1.z; xv[7] = v1.w;
        } else { xv[4] = xv[5] = xv[6] = xv[7] = 0.f; }
        short8 a, a2;
        #pragma unroll
        for (int e = 0; e < 8; e++) {
            a[e]  = (short)f2bf(xv[e]);
            a2[e] = (short)f2bf(xv[e] * xv[e]);
        }
        const short8* p1 = b1 + (size_t)(15 * 4) * 64 + l;
        const short8* p2 = b2 + (size_t)(15 * 2) * 64 + l;
        acc0 = __builtin_amdgcn_mfma_f32_16x16x32_bf16(a,  p1[0],   acc0, 0, 0, 0);
        acc1 = __builtin_amdgcn_mfma_f32_16x16x32_bf16(a,  p1[64],  acc1, 0, 0, 0);
        acc2 = __builtin_amdgcn_mfma_f32_16x16x32_bf16(a,  p1[128], acc2, 0, 0, 0);
        acc3 = __builtin_amdgcn_mfma_f32_16x16x32_bf16(a,  p1[192], acc3, 0, 0, 0);
        acc0 = __builtin_amdgcn_mfma_f32_16x16x32_bf16(a2, p2[0],   acc0, 0, 0, 0);
        acc1 = __builtin_amdgcn_mfma_f32_16x16x32_bf16(a2, p2[64],  acc1, 0, 0, 0);
    }

    // C layout: row = grp*4 + reg, col = nt*16 + j  (m89-verified)
    __shared__ float ct[4][16][68];
    #pragma unroll
    for (int r = 0; r < 4; r++) {
        ct[w][grp * 4 + r][j]      = acc0[r];
        ct[w][grp * 4 + r][16 + j] = acc1[r];
        ct[w][grp * 4 + r][32 + j] = acc2[r];
        ct[w][grp * 4 + r][48 + j] = acc3[r];
    }
    __syncthreads();

    float ll = 0.f;
    if (l < 16) {
        const int cell = rowbase + l;
        if (cell < NSUB) {
            const float* crow_lds = &ct[w][l][0];
            const int idx = sidx[cell];
            const float* wrow = Wp + (size_t)idx * NCLS;
            float p[NCLS];
            float mx = -1e30f;
            #pragma unroll
            for (int c = 0; c < NCLS; c++) { p[c] = wrow[c]; mx = fmaxf(mx, p[c]); }
            float sum = 0.f;
            #pragma unroll
            for (int c = 0; c < NCLS; c++) { p[c] = __expf(p[c] - mx); sum += p[c]; }
            const float inv = 1.0f / sum;
            const float s = Sp[idx];
            float* orow = out + 2 + (size_t)cell * NCLS;
            float* lrow = LP + (size_t)cell * NCLS;
            #pragma unroll
            for (int c = 0; c < NCLS; c++) {
                p[c] *= inv;
                orow[c] = p[c];
                lrow[c] = __logf(p[c] + 1e-8f);
                const float F = -0.5f * crow_lds[c] + s * crow_lds[NCLS + c]
                                - 0.5f * s * s * D[c];
                ll += p[c] * F;
            }
            #pragma unroll
            for (int h = 0; h < HIDN; h++) {
                XL[cell * HIDN + h] = crow_lds[34 + h] + bl[h];
                XR[cell * HIDN + h] = crow_lds[42 + h] + br[h];
            }
        }
    }
    #pragma unroll
    for (int o = 32; o; o >>= 1) ll += __shfl_xor(ll, o);
    if (l == 0) atomicAdd(out, ll * (1.0f / NSUB));
}

// ---------------- edge pass 1: e_k and segment max over dst ----------------
__device__ __forceinline__ unsigned f2ord(float f) {
    unsigned u = __float_as_uint(f);
    return (u & 0x80000000u) ? ~u : (u | 0x80000000u);
}
__device__ __forceinline__ float ord2f(unsigned o) {
    unsigned u = (o & 0x80000000u) ? (o ^ 0x80000000u) : ~o;
    return __uint_as_float(u);
}

__global__ void k_edge1(const int* __restrict__ ei, const float* __restrict__ XL,
                        const float* __restrict__ XR, const float* __restrict__ att,
                        float* __restrict__ E, unsigned* __restrict__ MORD) {
    const int k = blockIdx.x * 256 + threadIdx.x;
    if (k >= NE) return;
    const int s = ei[k], d = ei[NE + k];
    const float4 a0 = *reinterpret_cast<const float4*>(XL + s * HIDN);
    const float4 a1 = *reinterpret_cast<const float4*>(XL + s * HIDN + 4);
    const float4 b0 = *reinterpret_cast<const float4*>(XR + d * HIDN);
    const float4 b1 = *reinterpret_cast<const float4*>(XR + d * HIDN + 4);
    float hv[8] = { a0.x + b0.x, a0.y + b0.y, a0.z + b0.z, a0.w + b0.w,
                    a1.x + b1.x, a1.y + b1.y, a1.z + b1.z, a1.w + b1.w };
    float e = 0.f;
    #pragma unroll
    for (int h = 0; h < HIDN; h++) {
        float v = hv[h];
        v = (v > 0.f) ? v : NEG_SLOPE * v;
        e += v * att[h];
    }
    E[k] = e;
    atomicMax(MORD + d, f2ord(e));
}

// ---------------- edge pass 2: exp + weighted accumulation ----------------
__global__ void k_edge2(const int* __restrict__ ei, const float* __restrict__ out,
                        const float* __restrict__ LP, const float* __restrict__ E,
                        const unsigned* __restrict__ MORD,
                        float* __restrict__ NUM, float* __restrict__ DEN) {
    const int k = blockIdx.x * 256 + threadIdx.x;
    if (k >= NE) return;
    const int s = ei[k], d = ei[NE + k];
    const float m = ord2f(MORD[d]);
    const float ex = __expf(E[k] - m);
    const float* Ps = out + 2 + (size_t)s * NCLS;
    const float* Ld = LP + (size_t)d * NCLS;
    float wgt = 0.f;
    #pragma unroll
    for (int c = 0; c < NCLS; c++) wgt += Ps[c] * Ld[c];
    atomicAdd(NUM + d, ex * wgt);
    atomicAdd(DEN + d, ex);
}

// ---------------- node pass: ce_space = -sum(num/den)/n ----------------
__global__ void k_node(const float* __restrict__ NUM, const float* __restrict__ DEN,
                       float* __restrict__ out) {
    const int n = blockIdx.x * 256 + threadIdx.x;
    float v = 0.f;
    if (n < NSUB) {
        const float dd = DEN[n];
        if (dd > 0.f) v = NUM[n] / dd;
    }
    #pragma unroll
    for (int o = 32; o; o >>= 1) v += __shfl_xor(v, o);
    if ((threadIdx.x & 63) == 0) atomicAdd(out + 1, -v * (1.0f / NSUB));
}

extern "C" void kernel_launch(void* const* d_in, const int* in_sizes, int n_in,
                              void* d_out, int out_size, void* d_ws, size_t ws_size,
                              hipStream_t stream) {
    const float* x    = (const float*)d_in[0];
    const float* Mu   = (const float*)d_in[1];
    const float* Var  = (const float*)d_in[2];
    const int*   ei   = (const int*)d_in[3];
    const int*   sidx = (const int*)d_in[4];
    const float* Wp   = (const float*)d_in[5];
    const float* Sp   = (const float*)d_in[6];
    const float* Wl   = (const float*)d_in[7];
    const float* bl   = (const float*)d_in[8];
    const float* Wr   = (const float*)d_in[9];
    const float* br   = (const float*)d_in[10];
    const float* att  = (const float*)d_in[11];
    float* out = (float*)d_out;
    float* ws  = (float*)d_ws;

    unsigned short* B1 = (unsigned short*)(ws + OFF_B1);
    unsigned short* B2 = (unsigned short*)(ws + OFF_B2);
    float*    D    = ws + OFF_D;
    float*    XL   = ws + OFF_XL;
    float*    XR   = ws + OFF_XR;
    float*    LP   = ws + OFF_LP;
    float*    E    = ws + OFF_E;
    unsigned* MORD = (unsigned*)(ws + OFF_MORD);
    float*    NUM  = ws + OFF_NUM;
    float*    DEN  = ws + OFF_DEN;

    (void)in_sizes; (void)n_in; (void)out_size; (void)ws_size;

    // blocks: 4 (frag build) + 17 (D) + 118 (zeroing)
    k_prep<<<21 + (3 * NSUB + 255) / 256, 256, 0, stream>>>(Mu, Var, Wl, Wr, B1, B2, D,
                                                            ws + OFF_MORD, out);
    k_cell<<<(NSUB + 63) / 64, 256, 0, stream>>>(x, sidx, Wp, Sp, bl, br, B1, B2, D,
                                                 out, XL, XR, LP);
    k_edge1<<<(NE + 255) / 256, 256, 0, stream>>>(ei, XL, XR, att, E, MORD);
    k_edge2<<<(NE + 255) / 256, 256, 0, stream>>>(ei, out, LP, E, MORD, NUM, DEN);
    k_node<<<(NSUB + 255) / 256, 256, 0, stream>>>(NUM, DEN, out);
}